// Round 8
// baseline (482.557 us; speedup 1.0000x reference)
//
#include <hip/hip_runtime.h>
#include <math.h>

#define N_NODES 50000
#define N_EDGES 1200000
#define BATCH   64
#define D       64
#define EPS     1e-12f
#define NCOPY   64
#define PSZ     (NCOPY * BATCH * D)   // floats per pool replica set (1 MB)

#define EB  2344                      // prologue edge blocks (2344*512 >= N_EDGES)
#define MMB 8                         // prologue weight-fuse blocks
#define IB  6258                      // prologue init blocks (6258*8 >= 50064 rows)
#define NODE_BLOCKS 1563              // 1563 blocks * 8 waves * 4 rows >= 50000
#define NW4 12500                     // 4-row wave groups (50000/4)

__device__ __forceinline__ int rfl(int v) { return __builtin_amdgcn_readfirstlane(v); }

// ---------------------------------------------------------------------------
// Prologue (one dispatch):
//  blocks [0,EB):        zero both pool replica sets + scatter row_start
//  blocks [EB,EB+MMB):   fused weights MM4[kk][j] = {M2[2kk][j],M3[2kk][j],M2[2kk+1][j],M3[2kk+1][j]}
//  blocks [EB+MMB, ...): h0 = l2norm(relu(X@W1)) -> B0 ; hs0 -> HS   (no pooling!)
// ---------------------------------------------------------------------------
__global__ void __launch_bounds__(512) k_pro(const int* __restrict__ edge_row,
                                             int* __restrict__ row_start,
                                             float* __restrict__ PA, float* __restrict__ PB,
                                             const float* __restrict__ W2,
                                             const float* __restrict__ W3,
                                             const float* __restrict__ Wl,
                                             float* __restrict__ MM4,
                                             const float* __restrict__ X,
                                             const float* __restrict__ Xs,
                                             const float* __restrict__ W1,
                                             float* __restrict__ B0,
                                             float* __restrict__ HS) {
    int bid = blockIdx.x, t = threadIdx.x;
    if (bid < EB) {
        int tid = bid * 512 + t;
        for (int i = tid; i < PSZ; i += EB * 512) { PA[i] = 0.f; PB[i] = 0.f; }
        if (tid < N_EDGES) {
            int b = edge_row[tid];
            int a = (tid == 0) ? -1 : edge_row[tid - 1];
            for (int r = a + 1; r <= b; ++r) row_start[r] = tid;   // first edge with row >= r
            if (tid == N_EDGES - 1)
                for (int r = b + 1; r <= N_NODES; ++r) row_start[r] = N_EDGES;
        }
    } else if (bid < EB + MMB) {
        int k = (bid - EB) * 8 + (t >> 6), j = t & 63;
        float a2 = 0.f, a3 = 0.f;
        for (int q = 0; q < D; ++q) {
            a2 += W2[k*D + q] * Wl[q*D + j];
            a3 += W3[k*D + q] * Wl[(D + q)*D + j];
        }
        MM4[(k >> 1) * (D * 4) + j * 4 + (k & 1) * 2 + 0] = a2;
        MM4[(k >> 1) * (D * 4) + j * 4 + (k & 1) * 2 + 1] = a3;
    } else {
        int row = (bid - EB - MMB) * 8 + (t >> 6);
        int j = t & 63;
        if (row >= N_NODES + BATCH) return;
        float x0, x1; float* out;
        if (row < N_NODES) {
            x0 = X[row*2]; x1 = X[row*2 + 1]; out = B0 + (size_t)row * D;
        } else {
            int r = row - N_NODES;
            x0 = Xs[r*2]; x1 = Xs[r*2 + 1]; out = HS + (size_t)r * D;
        }
        float v = fmaxf(fmaf(x0, W1[j], x1 * W1[D + j]), 0.f);
        float ss = v * v;
        #pragma unroll
        for (int off = 32; off; off >>= 1) ss += __shfl_xor(ss, off);
        out[j] = v / fmaxf(sqrtf(ss), EPS);
    }
}

// ---------------------------------------------------------------------------
// Fused iteration. Blocks [0,hs_blocks): hs update consuming Pin replicas
// (re-zeroing them). Blocks [hs_blocks, hs_blocks+NODE_BLOCKS): one wave = 4
// adjacent node rows: gather (1 index vector-load per 64 edges, readlane ->
// saddr gathers, uniform 4-way routing), input-pool hv into Pout replicas,
// then shared dense phase: LDS-broadcast GEMV (MM float4 k-pairs), relu,
// wave l2norm, store.
// ---------------------------------------------------------------------------
__global__ void __launch_bounds__(512, 6) k_iter(const int* __restrict__ edge_col,
                                                 const int* __restrict__ row_start,
                                                 const float* __restrict__ Hc,
                                                 float* __restrict__ Hn,
                                                 const float* __restrict__ MM4,
                                                 const float* __restrict__ bl,
                                                 const int* __restrict__ batch,
                                                 float* __restrict__ Pout,
                                                 float* __restrict__ HSrw,
                                                 float* __restrict__ Pin,
                                                 int hs_blocks) {
    __shared__ float4 sMM[32 * 64];   // 32 KB
    __shared__ float4 sH[8 * 64];     // 8 KB
    __shared__ float4 sG[8 * 64];     // 8 KB
    int t = threadIdx.x, w = t >> 6, l = t & 63;
    const float4* gMM = (const float4*)MM4;
    for (int i = t; i < 2048; i += 512) sMM[i] = gMM[i];
    __syncthreads();

    int bid = blockIdx.x;
    bool is_hs = (bid < hs_blocks);
    float hv0, hv1, hv2, hv3, gv0, gv1, gv2, gv3;
    int rbase;

    if (!is_hs) {
        int g4 = (bid - hs_blocks) * 8 + w;
        if (g4 >= NW4) return;
        rbase = g4 * 4;
        int eS  = rfl(row_start[rbase]);
        int eA  = rfl(row_start[rbase + 1]);
        int eBb = rfl(row_start[rbase + 2]);
        int eC  = rfl(row_start[rbase + 3]);
        int eD_ = rfl(row_start[rbase + 4]);
        hv0 = Hc[(size_t)(rbase + 0) * D + l];
        hv1 = Hc[(size_t)(rbase + 1) * D + l];
        hv2 = Hc[(size_t)(rbase + 2) * D + l];
        hv3 = Hc[(size_t)(rbase + 3) * D + l];
        float aA = 0.f, aB = 0.f, aC = 0.f, aD = 0.f;
        for (int base = eS; base < eD_; base += 64) {
            int cw = eD_ - base; if (cw > 64) cw = 64;
            int col = 0;
            if (l < cw) col = edge_col[base + l];
            int nb = (cw + 15) >> 4;
            for (int b = 0; b < nb; ++b) {
                #pragma unroll
                for (int u = 0; u < 16; ++u) {
                    int o = (b << 4) + u;
                    int eidx = base + o;
                    if (eidx < eD_) {                       // uniform guard
                        int c = __builtin_amdgcn_readlane(col, o);
                        float v = Hc[(size_t)c * D + l];    // uniform base -> saddr
                        if (eidx < eA)       aA += v;       // uniform routing
                        else if (eidx < eBb) aB += v;
                        else if (eidx < eC)  aC += v;
                        else                 aD += v;
                    }
                }
            }
        }
        gv0 = aA; gv1 = aB; gv2 = aC; gv3 = aD;
        // producer-side pooling of the INPUT h rows (consumed by NEXT kernel's hs)
        float* cp = Pout + (size_t)(bid & (NCOPY - 1)) * (BATCH * D);
        int b0 = rfl(batch[rbase + 0]);
        int b1 = rfl(batch[rbase + 1]);
        int b2 = rfl(batch[rbase + 2]);
        int b3 = rfl(batch[rbase + 3]);
        atomicAdd(&cp[b0 * D + l], hv0);
        atomicAdd(&cp[b1 * D + l], hv1);
        atomicAdd(&cp[b2 * D + l], hv2);
        atomicAdd(&cp[b3 * D + l], hv3);
    } else {
        int g4 = bid * 8 + w;
        if (g4 >= 16) return;                 // 16 waves cover 64 hs rows
        rbase = g4 * 4;
        hv0 = HSrw[(size_t)(rbase + 0) * D + l];
        hv1 = HSrw[(size_t)(rbase + 1) * D + l];
        hv2 = HSrw[(size_t)(rbase + 2) * D + l];
        hv3 = HSrw[(size_t)(rbase + 3) * D + l];
        float aA = 0.f, aB = 0.f, aC = 0.f, aD = 0.f;
        #pragma unroll 4
        for (int c = 0; c < NCOPY; ++c) {
            float* p = Pin + (size_t)c * (BATCH * D) + rbase * D + l;
            float v0 = p[0], v1 = p[D], v2 = p[2*D], v3 = p[3*D];
            p[0] = 0.f; p[D] = 0.f; p[2*D] = 0.f; p[3*D] = 0.f;   // re-zero for reuse
            aA += v0; aB += v1; aC += v2; aD += v3;
        }
        gv0 = aA; gv1 = aB; gv2 = aC; gv3 = aD;
    }

    // ---- dense: 4 rows [h|g] @ [M2;M3] + bl, LDS-broadcast, no readlanes ----
    sH[w * 64 + l] = make_float4(hv0, hv1, hv2, hv3);
    sG[w * 64 + l] = make_float4(gv0, gv1, gv2, gv3);
    float bj = bl[l];
    float a2A = 0.f, a2B = 0.f, a2C = 0.f, a2D = 0.f;
    float a3A = bj,  a3B = bj,  a3C = bj,  a3D = bj;
    const float4* ph = &sH[w * 64];
    const float4* pg = &sG[w * 64];
    #pragma unroll
    for (int kk = 0; kk < 32; ++kk) {
        float4 mm = sMM[kk * 64 + l];
        float4 h0 = ph[2 * kk], h1 = ph[2 * kk + 1];
        float4 g0 = pg[2 * kk], g1 = pg[2 * kk + 1];
        a2A = fmaf(h0.x, mm.x, a2A); a2B = fmaf(h0.y, mm.x, a2B);
        a2C = fmaf(h0.z, mm.x, a2C); a2D = fmaf(h0.w, mm.x, a2D);
        a3A = fmaf(g0.x, mm.y, a3A); a3B = fmaf(g0.y, mm.y, a3B);
        a3C = fmaf(g0.z, mm.y, a3C); a3D = fmaf(g0.w, mm.y, a3D);
        a2A = fmaf(h1.x, mm.z, a2A); a2B = fmaf(h1.y, mm.z, a2B);
        a2C = fmaf(h1.z, mm.z, a2C); a2D = fmaf(h1.w, mm.z, a2D);
        a3A = fmaf(g1.x, mm.w, a3A); a3B = fmaf(g1.y, mm.w, a3B);
        a3C = fmaf(g1.z, mm.w, a3C); a3D = fmaf(g1.w, mm.w, a3D);
    }
    float v0 = fmaxf(a2A + a3A, 0.f);
    float v1 = fmaxf(a2B + a3B, 0.f);
    float v2 = fmaxf(a2C + a3C, 0.f);
    float v3 = fmaxf(a2D + a3D, 0.f);
    float s0 = v0*v0, s1 = v1*v1, s2 = v2*v2, s3 = v3*v3;
    #pragma unroll
    for (int off = 32; off; off >>= 1) {
        s0 += __shfl_xor(s0, off); s1 += __shfl_xor(s1, off);
        s2 += __shfl_xor(s2, off); s3 += __shfl_xor(s3, off);
    }
    v0 /= fmaxf(sqrtf(s0), EPS); v1 /= fmaxf(sqrtf(s1), EPS);
    v2 /= fmaxf(sqrtf(s2), EPS); v3 /= fmaxf(sqrtf(s3), EPS);
    float* out = is_hs ? HSrw : Hn;
    out[(size_t)(rbase + 0) * D + l] = v0;
    out[(size_t)(rbase + 1) * D + l] = v1;
    out[(size_t)(rbase + 2) * D + l] = v2;
    out[(size_t)(rbase + 3) * D + l] = v3;
}

// ---------------------------------------------------------------------------
extern "C" void kernel_launch(void* const* d_in, const int* in_sizes, int n_in,
                              void* d_out, int out_size, void* d_ws, size_t ws_size,
                              hipStream_t stream) {
    const int*   edge_row = (const int*)  d_in[0];
    const int*   edge_col = (const int*)  d_in[1];
    const int*   batch    = (const int*)  d_in[2];
    const float* X        = (const float*)d_in[3];
    const float* Xs       = (const float*)d_in[4];
    const float* W1       = (const float*)d_in[5];
    const float* W2       = (const float*)d_in[6];
    const float* W3       = (const float*)d_in[7];
    const float* Wl       = (const float*)d_in[8];
    const float* bl       = (const float*)d_in[9];

    float* H  = (float*)d_out;                        // final node embeddings
    float* HS = (float*)d_out + (size_t)N_NODES * D;  // hs (updated in place)

    float* B0  = (float*)d_ws;                          // N_NODES*D
    float* B1  = B0 + (size_t)N_NODES * D;              // N_NODES*D
    float* PA  = B1 + (size_t)N_NODES * D;              // PSZ
    float* PB  = PA + PSZ;                              // PSZ
    float* MM4 = PB + PSZ;                              // 32*64*4 floats
    int*   row_start = (int*)(MM4 + 32 * 64 * 4);       // N_NODES+1

    // prologue: pools zeroed, row_start scattered, MM4 fused, h0/hs0 init
    k_pro<<<EB + MMB + IB, 512, 0, stream>>>(edge_row, row_start, PA, PB,
                                             W2, W3, Wl, MM4, X, Xs, W1, B0, HS);

    // iter 1: nodes h0(B0)->h1(B1), pool input h0 -> PA ; no hs blocks
    k_iter<<<NODE_BLOCKS, 512, 0, stream>>>(edge_col, row_start, B0, B1, MM4, bl,
                                            batch, PA, HS, PA, 0);
    // iter 2: nodes h1(B1)->h2(B0), pool input h1 -> PB ; hs consumes PA=pool(h0)
    k_iter<<<NODE_BLOCKS + 2, 512, 0, stream>>>(edge_col, row_start, B1, B0, MM4, bl,
                                                batch, PB, HS, PA, 2);
    // iter 3: nodes h2(B0)->h3(H), pool input h2 -> PA ; hs consumes PB=pool(h1)
    k_iter<<<NODE_BLOCKS + 2, 512, 0, stream>>>(edge_col, row_start, B0, H, MM4, bl,
                                                batch, PA, HS, PB, 2);
    // finale: hs only, consumes PA=pool(h2)
    k_iter<<<2, 512, 0, stream>>>(edge_col, row_start, B0, B0, MM4, bl,
                                  batch, PB, HS, PA, 2);
}

// Round 9
// 261.593 us; speedup vs baseline: 1.8447x; 1.8447x over previous
//
#include <hip/hip_runtime.h>
#include <math.h>

#define N_NODES 50000
#define N_EDGES 1200000
#define BATCH   64
#define D       64
#define EPS     1e-12f
#define NCOPY   64
#define PSZ     (NCOPY * BATCH * D)   // floats per pool replica set (1 MB)

#define EB  2344                      // prologue edge blocks (2344*512 >= N_EDGES)
#define MMB 8                         // prologue weight-fuse blocks
#define IB  6258                      // prologue init blocks (6258*8 >= 50064 rows)
#define NODE_BLOCKS 3125              // 3125 blocks * 8 waves * 2 rows = 50000
#define HSB 4                         // hs blocks: 4 * 8 waves * 2 rows = 64

__device__ __forceinline__ int rfl(int v) { return __builtin_amdgcn_readfirstlane(v); }

// ---------------------------------------------------------------------------
// Prologue (one dispatch):
//  blocks [0,EB):        zero both pool replica sets + scatter row_start
//  blocks [EB,EB+MMB):   fused weights MM4[kk][j] = {M2[2kk][j],M3[2kk][j],M2[2kk+1][j],M3[2kk+1][j]}
//  blocks [EB+MMB, ...): h0 = l2norm(relu(X@W1)) -> B0 ; hs0 -> HS   (no pooling)
// ---------------------------------------------------------------------------
__global__ void __launch_bounds__(512) k_pro(const int* __restrict__ edge_row,
                                             int* __restrict__ row_start,
                                             float* __restrict__ PA, float* __restrict__ PB,
                                             const float* __restrict__ W2,
                                             const float* __restrict__ W3,
                                             const float* __restrict__ Wl,
                                             float* __restrict__ MM4,
                                             const float* __restrict__ X,
                                             const float* __restrict__ Xs,
                                             const float* __restrict__ W1,
                                             float* __restrict__ B0,
                                             float* __restrict__ HS) {
    int bid = blockIdx.x, t = threadIdx.x;
    if (bid < EB) {
        int tid = bid * 512 + t;
        for (int i = tid; i < PSZ; i += EB * 512) { PA[i] = 0.f; PB[i] = 0.f; }
        if (tid < N_EDGES) {
            int b = edge_row[tid];
            int a = (tid == 0) ? -1 : edge_row[tid - 1];
            for (int r = a + 1; r <= b; ++r) row_start[r] = tid;   // first edge with row >= r
            if (tid == N_EDGES - 1)
                for (int r = b + 1; r <= N_NODES; ++r) row_start[r] = N_EDGES;
        }
    } else if (bid < EB + MMB) {
        int k = (bid - EB) * 8 + (t >> 6), j = t & 63;
        float a2 = 0.f, a3 = 0.f;
        for (int q = 0; q < D; ++q) {
            a2 += W2[k*D + q] * Wl[q*D + j];
            a3 += W3[k*D + q] * Wl[(D + q)*D + j];
        }
        MM4[(k >> 1) * (D * 4) + j * 4 + (k & 1) * 2 + 0] = a2;
        MM4[(k >> 1) * (D * 4) + j * 4 + (k & 1) * 2 + 1] = a3;
    } else {
        int row = (bid - EB - MMB) * 8 + (t >> 6);
        int j = t & 63;
        if (row >= N_NODES + BATCH) return;
        float x0, x1; float* out;
        if (row < N_NODES) {
            x0 = X[row*2]; x1 = X[row*2 + 1]; out = B0 + (size_t)row * D;
        } else {
            int r = row - N_NODES;
            x0 = Xs[r*2]; x1 = Xs[r*2 + 1]; out = HS + (size_t)r * D;
        }
        float v = fmaxf(fmaf(x0, W1[j], x1 * W1[D + j]), 0.f);
        float ss = v * v;
        #pragma unroll
        for (int off = 32; off; off >>= 1) ss += __shfl_xor(ss, off);
        out[j] = v / fmaxf(sqrtf(ss), EPS);
    }
}

// ---------------------------------------------------------------------------
// Fused iteration — round-6 measured structure (57us): one wave = 2 adjacent
// node rows; branch-free 16-deep gather batches (pad gathers row 0 into the
// B accumulator, subtracted afterward); uniform 2-way A/B routing; LDS
// broadcast GEMV dense phase. hs blocks (bid < hs_blocks) consume the Pin
// replicas (re-zeroing them). Node blocks pool their INPUT h rows into Pout
// for the NEXT dispatch's hs blocks.
// ---------------------------------------------------------------------------
__global__ void __launch_bounds__(512, 8) k_iter(const int* __restrict__ edge_col,
                                                 const int* __restrict__ row_start,
                                                 const float* __restrict__ Hc,
                                                 float* __restrict__ Hn,
                                                 const float* __restrict__ MM4,
                                                 const float* __restrict__ bl,
                                                 const int* __restrict__ batch,
                                                 float* __restrict__ Pout,
                                                 float* __restrict__ HSrw,
                                                 float* __restrict__ Pin,
                                                 int hs_blocks) {
    __shared__ float4 sMM[32 * 64];   // 32 KB
    __shared__ float4 sHG[8 * 64];    // 8 KB
    int t = threadIdx.x, w = t >> 6, l = t & 63;
    const float4* gMM = (const float4*)MM4;
    for (int i = t; i < 2048; i += 512) sMM[i] = gMM[i];
    __syncthreads();

    int bid = blockIdx.x;
    bool is_hs = (bid < hs_blocks);
    int rA, rB;
    float hvA, hvB, gvA, gvB;

    if (!is_hs) {
        int pr = (bid - hs_blocks) * 8 + w;   // pair index 0..24999
        rA = 2 * pr; rB = rA + 1;
        int sA = rfl(row_start[rA]);
        int eA = rfl(row_start[rB]);
        int eB = rfl(row_start[rB + 1]);
        hvA = Hc[(size_t)rA * D + l];
        hvB = Hc[(size_t)rB * D + l];
        float aA = 0.f, aB = 0.f;
        int pad = 0;
        for (int base = sA; base < eB; ) {
            int cw = eB - base; if (cw > 64) cw = 64;
            int col = 0;
            if (l < cw) col = edge_col[base + l];
            int nb = (cw + 15) >> 4;
            pad += (nb << 4) - cw;
            for (int b = 0; b < nb; ++b) {
                #pragma unroll
                for (int u = 0; u < 16; ++u) {
                    int idx = (b << 4) + u;
                    int c = __builtin_amdgcn_readlane(col, idx);
                    const float* rp = Hc + (size_t)c * D;   // uniform base -> saddr
                    float v = rp[l];
                    if (base + idx < eA) aA += v; else aB += v;   // uniform branch
                }
            }
            base += cw;
        }
        aB -= (float)pad * Hc[l];   // padding lanes gathered row 0 into the B side
        gvA = aA; gvB = aB;
        // producer-side pooling of INPUT h rows (consumed by NEXT dispatch's hs)
        float* cp = Pout + (size_t)(bid & (NCOPY - 1)) * (BATCH * D);
        int bA = rfl(batch[rA]);
        int bB = rfl(batch[rB]);
        atomicAdd(&cp[bA * D + l], hvA);
        atomicAdd(&cp[bB * D + l], hvB);
    } else {
        int pr = bid * 8 + w;                 // 0..31 -> hs rows 0..63
        rA = 2 * pr; rB = rA + 1;
        hvA = HSrw[(size_t)rA * D + l];
        hvB = HSrw[(size_t)rB * D + l];
        float aA = 0.f, aB = 0.f;
        #pragma unroll 4
        for (int c = 0; c < NCOPY; ++c) {
            float* p = Pin + (size_t)c * (BATCH * D) + rA * D + l;
            float vA = p[0], vB = p[D];
            p[0] = 0.f; p[D] = 0.f;   // re-zero replicas for reuse
            aA += vA; aB += vB;
        }
        gvA = aA; gvB = aB;
    }

    // ---- dense: [hA|gA],[hB|gB] @ [M2;M3] + bl, LDS-broadcast, no readlanes ----
    sHG[w * 64 + l] = make_float4(hvA, hvB, gvA, gvB);
    float bj = bl[l];
    float a2x = 0.f, a2y = 0.f, a3x = bj, a3y = bj;
    const float4* hg = &sHG[w * 64];
    #pragma unroll
    for (int kk = 0; kk < 32; ++kk) {
        float4 mm = sMM[kk * 64 + l];
        float4 h0 = hg[2 * kk];
        float4 h1 = hg[2 * kk + 1];
        a2x = fmaf(h0.x, mm.x, a2x); a2y = fmaf(h0.y, mm.x, a2y);
        a3x = fmaf(h0.z, mm.y, a3x); a3y = fmaf(h0.w, mm.y, a3y);
        a2x = fmaf(h1.x, mm.z, a2x); a2y = fmaf(h1.y, mm.z, a2y);
        a3x = fmaf(h1.z, mm.w, a3x); a3y = fmaf(h1.w, mm.w, a3y);
    }
    float vA = fmaxf(a2x + a3x, 0.f);
    float vB = fmaxf(a2y + a3y, 0.f);
    float ssA = vA * vA, ssB = vB * vB;
    #pragma unroll
    for (int off = 32; off; off >>= 1) {
        ssA += __shfl_xor(ssA, off);
        ssB += __shfl_xor(ssB, off);
    }
    float oA = vA / fmaxf(sqrtf(ssA), EPS);
    float oB = vB / fmaxf(sqrtf(ssB), EPS);

    float* out = is_hs ? HSrw : Hn;
    out[(size_t)rA * D + l] = oA;
    out[(size_t)rB * D + l] = oB;
}

// ---------------------------------------------------------------------------
extern "C" void kernel_launch(void* const* d_in, const int* in_sizes, int n_in,
                              void* d_out, int out_size, void* d_ws, size_t ws_size,
                              hipStream_t stream) {
    const int*   edge_row = (const int*)  d_in[0];
    const int*   edge_col = (const int*)  d_in[1];
    const int*   batch    = (const int*)  d_in[2];
    const float* X        = (const float*)d_in[3];
    const float* Xs       = (const float*)d_in[4];
    const float* W1       = (const float*)d_in[5];
    const float* W2       = (const float*)d_in[6];
    const float* W3       = (const float*)d_in[7];
    const float* Wl       = (const float*)d_in[8];
    const float* bl       = (const float*)d_in[9];

    float* H  = (float*)d_out;                        // final node embeddings
    float* HS = (float*)d_out + (size_t)N_NODES * D;  // hs (updated in place)

    float* B0  = (float*)d_ws;                          // N_NODES*D
    float* B1  = B0 + (size_t)N_NODES * D;              // N_NODES*D
    float* PA  = B1 + (size_t)N_NODES * D;              // PSZ
    float* PB  = PA + PSZ;                              // PSZ
    float* MM4 = PB + PSZ;                              // 32*64*4 floats
    int*   row_start = (int*)(MM4 + 32 * 64 * 4);       // N_NODES+1

    // prologue: pools zeroed, row_start scattered, MM4 fused, h0/hs0 init
    k_pro<<<EB + MMB + IB, 512, 0, stream>>>(edge_row, row_start, PA, PB,
                                             W2, W3, Wl, MM4, X, Xs, W1, B0, HS);

    // iter 1: nodes h0(B0)->h1(B1), pool input h0 -> PA ; no hs blocks
    k_iter<<<NODE_BLOCKS, 512, 0, stream>>>(edge_col, row_start, B0, B1, MM4, bl,
                                            batch, PA, HS, PA, 0);
    // iter 2: nodes h1(B1)->h2(B0), pool input h1 -> PB ; hs consumes PA=pool(h0)
    k_iter<<<NODE_BLOCKS + HSB, 512, 0, stream>>>(edge_col, row_start, B1, B0, MM4, bl,
                                                  batch, PB, HS, PA, HSB);
    // iter 3: nodes h2(B0)->h3(H), pool input h2 -> PA ; hs consumes PB=pool(h1)
    k_iter<<<NODE_BLOCKS + HSB, 512, 0, stream>>>(edge_col, row_start, B0, H, MM4, bl,
                                                  batch, PA, HS, PB, HSB);
    // finale: hs only, consumes PA=pool(h2)
    k_iter<<<HSB, 512, 0, stream>>>(edge_col, row_start, B0, B0, MM4, bl,
                                    batch, PB, HS, PA, HSB);
}